// Round 1
// baseline (434.581 us; speedup 1.0000x reference)
//
#include <hip/hip_runtime.h>
#include <stdint.h>

typedef __attribute__((ext_vector_type(8))) short short8;
typedef __attribute__((ext_vector_type(4))) float float4v;
typedef unsigned short u16;

#define N_TOK 2048
#define D_MODEL 1024
#define N_HEAD 8
#define HDIM 128
#define N_BUCKET 64

__device__ __forceinline__ u16 f2bf(float f) {
  uint32_t u = __float_as_uint(f);
  uint32_t r = u + 0x7fffu + ((u >> 16) & 1u);
  return (u16)(r >> 16);
}
__device__ __forceinline__ float bf2f(u16 h) {
  return __uint_as_float(((uint32_t)h) << 16);
}

__device__ __forceinline__ void async_load16(const void* g, void* l) {
  __builtin_amdgcn_global_load_lds(
      (const __attribute__((address_space(1))) void*)g,
      (__attribute__((address_space(3))) void*)l, 16, 0, 0);
}

// ---------- elementwise f32 -> bf16 hi (+ optional lo residual) ----------
__global__ __launch_bounds__(256) void split_cast_kernel(
    const float* __restrict__ in, u16* __restrict__ hi, u16* __restrict__ lo,
    int n) {
  int i = blockIdx.x * 256 + threadIdx.x;
  if (i >= n) return;
  float v = in[i];
  u16 h = f2bf(v);
  hi[i] = h;
  if (lo) lo[i] = f2bf(v - bf2f(h));
}

// ---------- transpose + cast: in[R][C] f32 -> hi/lo [C][R] bf16 ----------
__global__ __launch_bounds__(256) void transpose_split_kernel(
    const float* __restrict__ in, u16* __restrict__ hi, u16* __restrict__ lo,
    int R, int C) {
  __shared__ float tile[32][33];
  int c0 = blockIdx.x * 32, r0 = blockIdx.y * 32;
  int tx = threadIdx.x, ty = threadIdx.y;  // 32 x 8
#pragma unroll
  for (int i = 0; i < 4; i++) {
    int rl = ty + i * 8;
    tile[rl][tx] = in[(size_t)(r0 + rl) * C + c0 + tx];
  }
  __syncthreads();
#pragma unroll
  for (int i = 0; i < 4; i++) {
    int cl = ty + i * 8;
    float v = tile[tx][cl];
    size_t oidx = (size_t)(c0 + cl) * R + r0 + tx;
    u16 h = f2bf(v);
    hi[oidx] = h;
    if (lo) lo[oidx] = f2bf(v - bf2f(h));
  }
}

// ---------- GEMM: C[M,N] f32 (+)= A[M,K]bf16 * Bt[N,K]bf16^T (+bias) ----
// flags: 1 = accumulate into C, 2 = add bias
__global__ __launch_bounds__(256) void gemm_bf16_kernel(
    const u16* __restrict__ A, const u16* __restrict__ Bt,
    float* __restrict__ C, const float* __restrict__ bias,
    int M, int N, int K, int flags) {
  __shared__ __align__(16) u16 As[128 * 32];
  __shared__ __align__(16) u16 Bs[128 * 32];
  const int tid = threadIdx.x;
  const int wave = tid >> 6, lane = tid & 63;
  const int lhi = lane >> 4, llo = lane & 15;
  const int nbn = N >> 7;
  const int bm = (blockIdx.x / nbn) << 7;
  const int bn = (blockIdx.x % nbn) << 7;
  const int wm = (wave >> 1) << 6;
  const int wn = (wave & 1) << 6;

  float4v acc[4][4];
#pragma unroll
  for (int mi = 0; mi < 4; mi++)
#pragma unroll
    for (int ni = 0; ni < 4; ni++)
#pragma unroll
      for (int r = 0; r < 4; r++) acc[mi][ni][r] = 0.f;

  const int arow = lane >> 2;         // row within 16-row chunk
  const int acolb = (lane & 3) * 16;  // byte offset within 64B row

  for (int ko = 0; ko < K; ko += 32) {
#pragma unroll
    for (int cc = 0; cc < 2; cc++) {
      int c = wave + cc * 4;          // chunk 0..7, wave-uniform
      int row = c * 16 + arow;
      const char* ga = (const char*)A + ((size_t)(bm + row) * K + ko) * 2 + acolb;
      const char* gb = (const char*)Bt + ((size_t)(bn + row) * K + ko) * 2 + acolb;
      async_load16(ga, (char*)As + c * 1024);
      async_load16(gb, (char*)Bs + c * 1024);
    }
    __syncthreads();
    short8 af[4], bf[4];
#pragma unroll
    for (int i = 0; i < 4; i++) {
      af[i] = *(const short8*)&As[(wm + i * 16 + llo) * 32 + lhi * 8];
      bf[i] = *(const short8*)&Bs[(wn + i * 16 + llo) * 32 + lhi * 8];
    }
#pragma unroll
    for (int mi = 0; mi < 4; mi++)
#pragma unroll
      for (int ni = 0; ni < 4; ni++)
        acc[mi][ni] = __builtin_amdgcn_mfma_f32_16x16x32_bf16(af[mi], bf[ni],
                                                              acc[mi][ni], 0, 0, 0);
    __syncthreads();
  }

#pragma unroll
  for (int mi = 0; mi < 4; mi++)
#pragma unroll
    for (int ni = 0; ni < 4; ni++) {
      int row0 = bm + wm + mi * 16 + lhi * 4;
      int col = bn + wn + ni * 16 + llo;
      float bb = (flags & 2) ? bias[col] : 0.f;
      float* cp = C + (size_t)row0 * N + col;
#pragma unroll
      for (int r = 0; r < 4; r++) {
        float v = acc[mi][ni][r] + bb;
        if (flags & 1) v += cp[(size_t)r * N];
        cp[(size_t)r * N] = v;
      }
    }
}

// ---------- hash scores + argmax -> bucket[H][N] ----------
__global__ __launch_bounds__(512) void hash_argmax_kernel(
    const float* __restrict__ Q, const float* __restrict__ proj,
    int* __restrict__ bucket) {
  int n = blockIdx.x;
  int hh = threadIdx.x >> 6;  // wave == head
  int f = threadIdx.x & 63;
  const float* qp = Q + (size_t)n * D_MODEL + hh * HDIM;
  const float* pp = proj + (size_t)hh * HDIM * N_BUCKET + f;
  float s = 0.f;
#pragma unroll 4
  for (int d = 0; d < HDIM; d++) s += qp[d] * pp[(size_t)d * N_BUCKET];
  int idx = f;
#pragma unroll
  for (int off = 32; off > 0; off >>= 1) {
    float ov = __shfl_xor(s, off);
    int oi = __shfl_xor(idx, off);
    if (ov > s || (ov == s && oi < idx)) { s = ov; idx = oi; }
  }
  if (f == 0) bucket[hh * N_TOK + n] = idx;
}

// ---------- bucket-masked flash attention ----------
// qb,kb: [N,D] bf16 ; vt: [D][N] bf16 (per-head rows h*128..); o: [N,D] f32
__global__ __launch_bounds__(256) void attn_kernel(
    const u16* __restrict__ qb, const u16* __restrict__ kb,
    const u16* __restrict__ vt, const int* __restrict__ bucket,
    float* __restrict__ o) {
  const int h = blockIdx.y;
  const int wave = threadIdx.x >> 6, lane = threadIdx.x & 63;
  const int lhi = lane >> 4, llo = lane & 15;
  const int qrow0 = blockIdx.x * 64 + wave * 16;
  __shared__ __align__(16) u16 P_lds[4][16][64];

  short8 qf[4];
#pragma unroll
  for (int kf = 0; kf < 4; kf++)
    qf[kf] = *(const short8*)&qb[(size_t)(qrow0 + llo) * D_MODEL + h * HDIM +
                                 kf * 32 + lhi * 8];

  int bq[4];
#pragma unroll
  for (int r = 0; r < 4; r++) bq[r] = bucket[h * N_TOK + qrow0 + lhi * 4 + r];

  float m[4], l[4];
#pragma unroll
  for (int r = 0; r < 4; r++) { m[r] = -INFINITY; l[r] = 0.f; }
  float4v accO[8];
#pragma unroll
  for (int d = 0; d < 8; d++)
#pragma unroll
    for (int r = 0; r < 4; r++) accO[d][r] = 0.f;

  const float scale = 0.08838834764831845f;  // 1/sqrt(128)

  for (int kv = 0; kv < N_TOK; kv += 64) {
    float4v s[4];
#pragma unroll
    for (int nf = 0; nf < 4; nf++)
#pragma unroll
      for (int r = 0; r < 4; r++) s[nf][r] = 0.f;
#pragma unroll
    for (int nf = 0; nf < 4; nf++)
#pragma unroll
      for (int kf = 0; kf < 4; kf++) {
        short8 kfr = *(const short8*)&kb[(size_t)(kv + nf * 16 + llo) * D_MODEL +
                                         h * HDIM + kf * 32 + lhi * 8];
        s[nf] = __builtin_amdgcn_mfma_f32_16x16x32_bf16(qf[kf], kfr, s[nf], 0, 0, 0);
      }
    int bk[4];
#pragma unroll
    for (int nf = 0; nf < 4; nf++) bk[nf] = bucket[h * N_TOK + kv + nf * 16 + llo];

    float tmax[4];
#pragma unroll
    for (int r = 0; r < 4; r++) tmax[r] = -INFINITY;
#pragma unroll
    for (int nf = 0; nf < 4; nf++)
#pragma unroll
      for (int r = 0; r < 4; r++) {
        float v = s[nf][r] * scale;
        v = (bq[r] == bk[nf]) ? v : -1e30f;
        s[nf][r] = v;
        tmax[r] = fmaxf(tmax[r], v);
      }
#pragma unroll
    for (int r = 0; r < 4; r++)
#pragma unroll
      for (int off = 1; off < 16; off <<= 1)
        tmax[r] = fmaxf(tmax[r], __shfl_xor(tmax[r], off));

    float resc[4], psum[4];
#pragma unroll
    for (int r = 0; r < 4; r++) {
      float mn = fmaxf(m[r], tmax[r]);
      resc[r] = __expf(m[r] - mn);
      m[r] = mn;
      psum[r] = 0.f;
    }
#pragma unroll
    for (int nf = 0; nf < 4; nf++)
#pragma unroll
      for (int r = 0; r < 4; r++) {
        float p = __expf(s[nf][r] - m[r]);
        psum[r] += p;
        P_lds[wave][lhi * 4 + r][nf * 16 + llo] = f2bf(p);
      }
#pragma unroll
    for (int r = 0; r < 4; r++) {
#pragma unroll
      for (int off = 1; off < 16; off <<= 1) psum[r] += __shfl_xor(psum[r], off);
      l[r] = l[r] * resc[r] + psum[r];
    }
#pragma unroll
    for (int d = 0; d < 8; d++)
#pragma unroll
      for (int r = 0; r < 4; r++) accO[d][r] *= resc[r];

    asm volatile("s_waitcnt lgkmcnt(0)" ::: "memory");  // P_lds writes visible
    short8 pf[2];
#pragma unroll
    for (int k2 = 0; k2 < 2; k2++)
      pf[k2] = *(const short8*)&P_lds[wave][llo][k2 * 32 + lhi * 8];
#pragma unroll
    for (int d = 0; d < 8; d++)
#pragma unroll
      for (int k2 = 0; k2 < 2; k2++) {
        short8 vfr = *(const short8*)&vt[(size_t)(h * HDIM + d * 16 + llo) * N_TOK +
                                         kv + k2 * 32 + lhi * 8];
        accO[d] = __builtin_amdgcn_mfma_f32_16x16x32_bf16(pf[k2], vfr, accO[d], 0, 0, 0);
      }
    asm volatile("" ::: "memory");
  }
#pragma unroll
  for (int d = 0; d < 8; d++)
#pragma unroll
    for (int r = 0; r < 4; r++) {
      int row = qrow0 + lhi * 4 + r;
      int col = h * HDIM + d * 16 + llo;
      o[(size_t)row * D_MODEL + col] = accO[d][r] / l[r];
    }
}

extern "C" void kernel_launch(void* const* d_in, const int* in_sizes, int n_in,
                              void* d_out, int out_size, void* d_ws, size_t ws_size,
                              hipStream_t stream) {
  const float* x  = (const float*)d_in[0];
  const float* Wq = (const float*)d_in[1];
  const float* bq = (const float*)d_in[2];
  const float* Wk = (const float*)d_in[3];
  const float* bk = (const float*)d_in[4];
  const float* Wv = (const float*)d_in[5];
  const float* bv = (const float*)d_in[6];
  const float* Wo = (const float*)d_in[7];
  const float* bo = (const float*)d_in[8];
  const float* hp = (const float*)d_in[9];
  float* out = (float*)d_out;

  char* ws = (char*)d_ws;
  size_t off = 0;
  auto alloc = [&](size_t b) {
    char* p = ws + off;
    off += (b + 255) & ~(size_t)255;
    return p;
  };

  const int N = N_TOK, D = D_MODEL;
  u16* xhi    = (u16*)alloc((size_t)N * D * 2);
  u16* xlo    = (u16*)alloc((size_t)N * D * 2);
  u16* wqt_hi = (u16*)alloc((size_t)D * D * 2);
  u16* wqt_lo = (u16*)alloc((size_t)D * D * 2);
  u16* wkt    = (u16*)alloc((size_t)D * D * 2);
  u16* wvt    = (u16*)alloc((size_t)D * D * 2);
  u16* wot    = (u16*)alloc((size_t)D * D * 2);
  float* Qf   = (float*)alloc((size_t)N * D * 4);
  float* Kf   = (float*)alloc((size_t)N * D * 4);
  float* Vf   = (float*)alloc((size_t)N * D * 4);
  u16* qbb    = (u16*)alloc((size_t)N * D * 2);
  u16* kbb    = (u16*)alloc((size_t)N * D * 2);
  u16* vtb    = (u16*)alloc((size_t)D * N * 2);
  int* bucket = (int*)alloc((size_t)N_HEAD * N * 4);
  float* of   = (float*)alloc((size_t)N * D * 4);
  u16* ob     = (u16*)alloc((size_t)N * D * 2);

  const int nelem = N * D;
  dim3 tb(32, 8);

  split_cast_kernel<<<(nelem + 255) / 256, 256, 0, stream>>>(x, xhi, xlo, nelem);
  transpose_split_kernel<<<dim3(D / 32, D / 32), tb, 0, stream>>>(Wq, wqt_hi, wqt_lo, D, D);
  transpose_split_kernel<<<dim3(D / 32, D / 32), tb, 0, stream>>>(Wk, wkt, nullptr, D, D);
  transpose_split_kernel<<<dim3(D / 32, D / 32), tb, 0, stream>>>(Wv, wvt, nullptr, D, D);
  transpose_split_kernel<<<dim3(D / 32, D / 32), tb, 0, stream>>>(Wo, wot, nullptr, D, D);

  const int gemm_grid = (N / 128) * (D / 128);
  // Q with hi/lo compensation (accurate for argmax), K/V plain bf16
  gemm_bf16_kernel<<<gemm_grid, 256, 0, stream>>>(xhi, wqt_hi, Qf, bq, N, D, D, 2);
  gemm_bf16_kernel<<<gemm_grid, 256, 0, stream>>>(xhi, wqt_lo, Qf, nullptr, N, D, D, 1);
  gemm_bf16_kernel<<<gemm_grid, 256, 0, stream>>>(xlo, wqt_hi, Qf, nullptr, N, D, D, 1);
  gemm_bf16_kernel<<<gemm_grid, 256, 0, stream>>>(xhi, wkt, Kf, bk, N, D, D, 2);
  gemm_bf16_kernel<<<gemm_grid, 256, 0, stream>>>(xhi, wvt, Vf, bv, N, D, D, 2);

  hash_argmax_kernel<<<N, 512, 0, stream>>>(Qf, hp, bucket);

  split_cast_kernel<<<(nelem + 255) / 256, 256, 0, stream>>>(Qf, qbb, nullptr, nelem);
  split_cast_kernel<<<(nelem + 255) / 256, 256, 0, stream>>>(Kf, kbb, nullptr, nelem);
  transpose_split_kernel<<<dim3(D / 32, N / 32), tb, 0, stream>>>(Vf, vtb, nullptr, N, D);

  attn_kernel<<<dim3(N / 64, N_HEAD), 256, 0, stream>>>(qbb, kbb, vtb, bucket, of);

  split_cast_kernel<<<(nelem + 255) / 256, 256, 0, stream>>>(of, ob, nullptr, nelem);
  gemm_bf16_kernel<<<gemm_grid, 256, 0, stream>>>(ob, wot, out, bo, N, D, D, 2);

  (void)in_sizes; (void)n_in; (void)out_size; (void)ws_size;
}

// Round 2
// 286.402 us; speedup vs baseline: 1.5174x; 1.5174x over previous
//
#include <hip/hip_runtime.h>
#include <stdint.h>

typedef __attribute__((ext_vector_type(8))) short short8;
typedef __attribute__((ext_vector_type(4))) short short4v;
typedef __attribute__((ext_vector_type(4))) float float4v;
typedef unsigned short u16;

#define N_TOK 2048
#define D_MODEL 1024
#define N_HEAD 8
#define HDIM 128
#define N_BUCKET 64
#define SPLITS 4
#define KV_PER (N_TOK / SPLITS)

__device__ __forceinline__ u16 f2bf(float f) {
  uint32_t u = __float_as_uint(f);
  uint32_t r = u + 0x7fffu + ((u >> 16) & 1u);
  return (u16)(r >> 16);
}
__device__ __forceinline__ float bf2f(u16 h) {
  return __uint_as_float(((uint32_t)h) << 16);
}

__device__ __forceinline__ void async_load16(const void* g, void* l) {
  __builtin_amdgcn_global_load_lds(
      (const __attribute__((address_space(1))) void*)g,
      (__attribute__((address_space(3))) void*)l, 16, 0, 0);
}

// ---------- elementwise f32 -> bf16 hi (+ optional lo residual) ----------
__global__ __launch_bounds__(256) void split_cast_kernel(
    const float* __restrict__ in, u16* __restrict__ hi, u16* __restrict__ lo,
    int n) {
  int i = blockIdx.x * 256 + threadIdx.x;
  if (i >= n) return;
  float v = in[i];
  u16 h = f2bf(v);
  hi[i] = h;
  if (lo) lo[i] = f2bf(v - bf2f(h));
}

// ---------- transpose + cast: in[R][C] f32 -> hi/lo [C][R] bf16 ----------
__global__ __launch_bounds__(256) void transpose_split_kernel(
    const float* __restrict__ in, u16* __restrict__ hi, u16* __restrict__ lo,
    int R, int C) {
  __shared__ float tile[32][33];
  int c0 = blockIdx.x * 32, r0 = blockIdx.y * 32;
  int tx = threadIdx.x, ty = threadIdx.y;  // 32 x 8
#pragma unroll
  for (int i = 0; i < 4; i++) {
    int rl = ty + i * 8;
    tile[rl][tx] = in[(size_t)(r0 + rl) * C + c0 + tx];
  }
  __syncthreads();
#pragma unroll
  for (int i = 0; i < 4; i++) {
    int cl = ty + i * 8;
    float v = tile[tx][cl];
    size_t oidx = (size_t)(c0 + cl) * R + r0 + tx;
    u16 h = f2bf(v);
    hi[oidx] = h;
    if (lo) lo[oidx] = f2bf(v - bf2f(h));
  }
}

// ---------- GEMM core fragment helpers ----------
// BM in {64,128}, BN = 128, BK = 32, 4 waves.
// BM=128: wave covers 64x64 (MI=4), wm=(wave>>1)*64, wn=(wave&1)*64
// BM=64 : wave covers 32x64 (MI=2), wm=(wave&1)*32,  wn=(wave>>1)*64

template <int BM>
__device__ __forceinline__ void stage_tiles(const u16* A, const u16* Bt,
                                            u16* As, u16* Bs, int bm, int bn,
                                            int K, int ko, int wave, int lane) {
  const int arow = lane >> 2;
  const int acolb = (lane & 3) * 16;
  constexpr int ACH = BM / 16;
  constexpr int PC = (ACH + 8) / 4;  // chunks per wave
#pragma unroll
  for (int cc = 0; cc < PC; cc++) {
    int idx = wave * PC + cc;
    if (idx < ACH) {
      int row = idx * 16 + arow;
      const char* g = (const char*)A + ((size_t)(bm + row) * K + ko) * 2 + acolb;
      async_load16(g, (char*)As + idx * 1024);
    } else {
      int row = (idx - ACH) * 16 + arow;
      const char* g = (const char*)Bt + ((size_t)(bn + row) * K + ko) * 2 + acolb;
      async_load16(g, (char*)Bs + (idx - ACH) * 1024);
    }
  }
}

// flags: 1 = accumulate into C, 2 = add bias, 4 = also write bf16 row-major,
//        8 = KV mode (col<1024 -> kbf bf16; col>=1024 -> vt transposed bf16; no C)
template <int BM>
__global__ __launch_bounds__(256) void gemm_bf16_kernel(
    const u16* __restrict__ A, const u16* __restrict__ Bt,
    float* __restrict__ C, const float* __restrict__ bias,
    const float* __restrict__ bias2, u16* __restrict__ kbf,
    u16* __restrict__ vt, int M, int N, int K, int flags) {
  constexpr int MI = BM / 32;
  __shared__ __align__(16) u16 As[BM * 32];
  __shared__ __align__(16) u16 Bs[128 * 32];
  const int tid = threadIdx.x;
  const int wave = tid >> 6, lane = tid & 63;
  const int lhi = lane >> 4, llo = lane & 15;
  const int nbn = N >> 7;
  const int bm = (blockIdx.x / nbn) * BM;
  const int bn = (blockIdx.x % nbn) << 7;
  const int wm = (BM == 128) ? (wave >> 1) * 64 : (wave & 1) * 32;
  const int wn = (BM == 128) ? (wave & 1) * 64 : (wave >> 1) * 64;

  float4v acc[MI][4];
#pragma unroll
  for (int mi = 0; mi < MI; mi++)
#pragma unroll
    for (int ni = 0; ni < 4; ni++)
#pragma unroll
      for (int r = 0; r < 4; r++) acc[mi][ni][r] = 0.f;

  for (int ko = 0; ko < K; ko += 32) {
    stage_tiles<BM>(A, Bt, As, Bs, bm, bn, K, ko, wave, lane);
    __syncthreads();
    short8 af[MI], bf[4];
#pragma unroll
    for (int i = 0; i < MI; i++)
      af[i] = *(const short8*)&As[(wm + i * 16 + llo) * 32 + lhi * 8];
#pragma unroll
    for (int i = 0; i < 4; i++)
      bf[i] = *(const short8*)&Bs[(wn + i * 16 + llo) * 32 + lhi * 8];
#pragma unroll
    for (int mi = 0; mi < MI; mi++)
#pragma unroll
      for (int ni = 0; ni < 4; ni++)
        acc[mi][ni] = __builtin_amdgcn_mfma_f32_16x16x32_bf16(af[mi], bf[ni],
                                                              acc[mi][ni], 0, 0, 0);
    __syncthreads();
  }

#pragma unroll
  for (int mi = 0; mi < MI; mi++)
#pragma unroll
    for (int ni = 0; ni < 4; ni++) {
      int row0 = bm + wm + mi * 16 + lhi * 4;
      int col = bn + wn + ni * 16 + llo;
      if (flags & 8) {  // KV epilogue
        if (col < 1024) {
          float bb = bias[col];
#pragma unroll
          for (int r = 0; r < 4; r++)
            kbf[(size_t)(row0 + r) * 1024 + col] = f2bf(acc[mi][ni][r] + bb);
        } else {
          int colv = col - 1024;
          float bb = bias2[colv];
          short4v pk;
#pragma unroll
          for (int r = 0; r < 4; r++) pk[r] = (short)f2bf(acc[mi][ni][r] + bb);
          *(short4v*)&vt[(size_t)colv * N_TOK + row0] = pk;
        }
      } else {
        float bb = (flags & 2) ? bias[col] : 0.f;
        float* cp = C + (size_t)row0 * N + col;
#pragma unroll
        for (int r = 0; r < 4; r++) {
          float v = acc[mi][ni][r] + bb;
          if (flags & 1) v += cp[(size_t)r * N];
          cp[(size_t)r * N] = v;
          if (flags & 4) kbf[(size_t)(row0 + r) * N + col] = f2bf(v);
        }
      }
    }
}

// ---------- fused 3-pass hi/lo GEMM for Q: C = A0*B0 + A0*B1 + A1*B0 + bias ----
__global__ __launch_bounds__(256) void gemm3_bf16_kernel(
    const u16* __restrict__ A0, const u16* __restrict__ A1,
    const u16* __restrict__ B0, const u16* __restrict__ B1,
    float* __restrict__ C, const float* __restrict__ bias,
    u16* __restrict__ bf_out, int M, int N, int K) {
  constexpr int BM = 64;
  constexpr int MI = 2;
  __shared__ __align__(16) u16 As[BM * 32];
  __shared__ __align__(16) u16 Bs[128 * 32];
  const int tid = threadIdx.x;
  const int wave = tid >> 6, lane = tid & 63;
  const int lhi = lane >> 4, llo = lane & 15;
  const int nbn = N >> 7;
  const int bm = (blockIdx.x / nbn) * BM;
  const int bn = (blockIdx.x % nbn) << 7;
  const int wm = (wave & 1) * 32;
  const int wn = (wave >> 1) * 64;

  float4v acc[MI][4];
#pragma unroll
  for (int mi = 0; mi < MI; mi++)
#pragma unroll
    for (int ni = 0; ni < 4; ni++)
#pragma unroll
      for (int r = 0; r < 4; r++) acc[mi][ni][r] = 0.f;

  for (int kk = 0; kk < 3 * 1024; kk += 32) {
    int p = kk >> 10;
    int ko = kk & 1023;
    const u16* Ap = (p == 2) ? A1 : A0;
    const u16* Bp = (p == 1) ? B1 : B0;
    stage_tiles<BM>(Ap, Bp, As, Bs, bm, bn, K, ko, wave, lane);
    __syncthreads();
    short8 af[MI], bf[4];
#pragma unroll
    for (int i = 0; i < MI; i++)
      af[i] = *(const short8*)&As[(wm + i * 16 + llo) * 32 + lhi * 8];
#pragma unroll
    for (int i = 0; i < 4; i++)
      bf[i] = *(const short8*)&Bs[(wn + i * 16 + llo) * 32 + lhi * 8];
#pragma unroll
    for (int mi = 0; mi < MI; mi++)
#pragma unroll
      for (int ni = 0; ni < 4; ni++)
        acc[mi][ni] = __builtin_amdgcn_mfma_f32_16x16x32_bf16(af[mi], bf[ni],
                                                              acc[mi][ni], 0, 0, 0);
    __syncthreads();
  }

#pragma unroll
  for (int mi = 0; mi < MI; mi++)
#pragma unroll
    for (int ni = 0; ni < 4; ni++) {
      int row0 = bm + wm + mi * 16 + lhi * 4;
      int col = bn + wn + ni * 16 + llo;
      float bb = bias[col];
#pragma unroll
      for (int r = 0; r < 4; r++) {
        float v = acc[mi][ni][r] + bb;
        C[(size_t)(row0 + r) * N + col] = v;
        bf_out[(size_t)(row0 + r) * N + col] = f2bf(v);
      }
    }
}

// ---------- hash scores + argmax -> bucket[H][N] ----------
__global__ __launch_bounds__(512) void hash_argmax_kernel(
    const float* __restrict__ Q, const float* __restrict__ proj,
    int* __restrict__ bucket) {
  int n = blockIdx.x;
  int hh = threadIdx.x >> 6;  // wave == head
  int f = threadIdx.x & 63;
  const float* qp = Q + (size_t)n * D_MODEL + hh * HDIM;
  const float* pp = proj + (size_t)hh * HDIM * N_BUCKET + f;
  float s = 0.f;
#pragma unroll 4
  for (int d = 0; d < HDIM; d++) s += qp[d] * pp[(size_t)d * N_BUCKET];
  int idx = f;
#pragma unroll
  for (int off = 32; off > 0; off >>= 1) {
    float ov = __shfl_xor(s, off);
    int oi = __shfl_xor(idx, off);
    if (ov > s || (ov == s && oi < idx)) { s = ov; idx = oi; }
  }
  if (f == 0) bucket[hh * N_TOK + n] = idx;
}

// ---------- bucket-masked flash attention, KV-split partials ----------
__global__ __launch_bounds__(256) void attn_split_kernel(
    const u16* __restrict__ qb, const u16* __restrict__ kb,
    const u16* __restrict__ vt, const int* __restrict__ bucket,
    float* __restrict__ Opart, float* __restrict__ Mpart,
    float* __restrict__ Lpart) {
  const int h = blockIdx.y;
  const int split = blockIdx.z;
  const int kv0 = split * KV_PER;
  const int wave = threadIdx.x >> 6, lane = threadIdx.x & 63;
  const int lhi = lane >> 4, llo = lane & 15;
  const int qrow0 = blockIdx.x * 64 + wave * 16;
  __shared__ __align__(16) u16 P_lds[4][16][64];

  short8 qf[4];
#pragma unroll
  for (int kf = 0; kf < 4; kf++)
    qf[kf] = *(const short8*)&qb[(size_t)(qrow0 + llo) * D_MODEL + h * HDIM +
                                 kf * 32 + lhi * 8];

  int bq[4];
#pragma unroll
  for (int r = 0; r < 4; r++) bq[r] = bucket[h * N_TOK + qrow0 + lhi * 4 + r];

  float m[4], l[4];
#pragma unroll
  for (int r = 0; r < 4; r++) { m[r] = -INFINITY; l[r] = 0.f; }
  float4v accO[8];
#pragma unroll
  for (int d = 0; d < 8; d++)
#pragma unroll
    for (int r = 0; r < 4; r++) accO[d][r] = 0.f;

  const float scale = 0.08838834764831845f;  // 1/sqrt(128)

  for (int kv = kv0; kv < kv0 + KV_PER; kv += 64) {
    float4v s[4];
#pragma unroll
    for (int nf = 0; nf < 4; nf++)
#pragma unroll
      for (int r = 0; r < 4; r++) s[nf][r] = 0.f;
    int bk[4];
#pragma unroll
    for (int nf = 0; nf < 4; nf++) bk[nf] = bucket[h * N_TOK + kv + nf * 16 + llo];
#pragma unroll
    for (int nf = 0; nf < 4; nf++)
#pragma unroll
      for (int kf = 0; kf < 4; kf++) {
        short8 kfr = *(const short8*)&kb[(size_t)(kv + nf * 16 + llo) * D_MODEL +
                                         h * HDIM + kf * 32 + lhi * 8];
        s[nf] = __builtin_amdgcn_mfma_f32_16x16x32_bf16(qf[kf], kfr, s[nf], 0, 0, 0);
      }

    float tmax[4];
#pragma unroll
    for (int r = 0; r < 4; r++) tmax[r] = -INFINITY;
#pragma unroll
    for (int nf = 0; nf < 4; nf++)
#pragma unroll
      for (int r = 0; r < 4; r++) {
        float v = s[nf][r] * scale;
        v = (bq[r] == bk[nf]) ? v : -1e30f;
        s[nf][r] = v;
        tmax[r] = fmaxf(tmax[r], v);
      }
#pragma unroll
    for (int r = 0; r < 4; r++)
#pragma unroll
      for (int off = 1; off < 16; off <<= 1)
        tmax[r] = fmaxf(tmax[r], __shfl_xor(tmax[r], off));

    float resc[4], psum[4];
#pragma unroll
    for (int r = 0; r < 4; r++) {
      float mn = fmaxf(m[r], tmax[r]);
      resc[r] = __expf(m[r] - mn);
      m[r] = mn;
      psum[r] = 0.f;
    }
#pragma unroll
    for (int nf = 0; nf < 4; nf++)
#pragma unroll
      for (int r = 0; r < 4; r++) {
        float p = __expf(s[nf][r] - m[r]);
        psum[r] += p;
        P_lds[wave][lhi * 4 + r][nf * 16 + llo] = f2bf(p);
      }
#pragma unroll
    for (int r = 0; r < 4; r++) {
#pragma unroll
      for (int off = 1; off < 16; off <<= 1) psum[r] += __shfl_xor(psum[r], off);
      l[r] = l[r] * resc[r] + psum[r];
    }
#pragma unroll
    for (int d = 0; d < 8; d++)
#pragma unroll
      for (int r = 0; r < 4; r++) accO[d][r] *= resc[r];

    asm volatile("s_waitcnt lgkmcnt(0)" ::: "memory");  // P_lds writes visible
    short8 pf[2];
#pragma unroll
    for (int k2 = 0; k2 < 2; k2++)
      pf[k2] = *(const short8*)&P_lds[wave][llo][k2 * 32 + lhi * 8];
#pragma unroll
    for (int d = 0; d < 8; d++)
#pragma unroll
      for (int k2 = 0; k2 < 2; k2++) {
        short8 vfr = *(const short8*)&vt[(size_t)(h * HDIM + d * 16 + llo) * N_TOK +
                                         kv + k2 * 32 + lhi * 8];
        accO[d] = __builtin_amdgcn_mfma_f32_16x16x32_bf16(pf[k2], vfr, accO[d], 0, 0, 0);
      }
    asm volatile("" ::: "memory");
  }

  float* Ob = Opart + (size_t)split * N_TOK * D_MODEL;
#pragma unroll
  for (int d = 0; d < 8; d++)
#pragma unroll
    for (int r = 0; r < 4; r++) {
      int row = qrow0 + lhi * 4 + r;
      int col = h * HDIM + d * 16 + llo;
      Ob[(size_t)row * D_MODEL + col] = accO[d][r];
    }
  if (llo == 0) {
#pragma unroll
    for (int r = 0; r < 4; r++) {
      int row = qrow0 + lhi * 4 + r;
      Mpart[((size_t)split * N_HEAD + h) * N_TOK + row] = m[r];
      Lpart[((size_t)split * N_HEAD + h) * N_TOK + row] = l[r];
    }
  }
}

// ---------- combine partials -> bf16 o ----------
__global__ __launch_bounds__(256) void combine_kernel(
    const float* __restrict__ Opart, const float* __restrict__ Mpart,
    const float* __restrict__ Lpart, u16* __restrict__ ob) {
  int idx = blockIdx.x * 256 + threadIdx.x;  // N*D/4 threads
  int n = idx >> 8;
  int c4 = idx & 255;
  int h = (c4 * 4) >> 7;
  float ms[SPLITS];
  float M = -INFINITY;
#pragma unroll
  for (int s = 0; s < SPLITS; s++) {
    ms[s] = Mpart[((size_t)s * N_HEAD + h) * N_TOK + n];
    M = fmaxf(M, ms[s]);
  }
  float L = 0.f;
  float o[4] = {0.f, 0.f, 0.f, 0.f};
#pragma unroll
  for (int s = 0; s < SPLITS; s++) {
    float w = __expf(ms[s] - M);
    L += Lpart[((size_t)s * N_HEAD + h) * N_TOK + n] * w;
    float4v op = *(const float4v*)&Opart[((size_t)s * N_TOK + n) * D_MODEL + c4 * 4];
#pragma unroll
    for (int j = 0; j < 4; j++) o[j] += op[j] * w;
  }
  float inv = 1.f / L;
  short4v pk;
#pragma unroll
  for (int j = 0; j < 4; j++) pk[j] = (short)f2bf(o[j] * inv);
  *(short4v*)&ob[(size_t)n * D_MODEL + c4 * 4] = pk;
}

extern "C" void kernel_launch(void* const* d_in, const int* in_sizes, int n_in,
                              void* d_out, int out_size, void* d_ws, size_t ws_size,
                              hipStream_t stream) {
  const float* x  = (const float*)d_in[0];
  const float* Wq = (const float*)d_in[1];
  const float* bq = (const float*)d_in[2];
  const float* Wk = (const float*)d_in[3];
  const float* bk = (const float*)d_in[4];
  const float* Wv = (const float*)d_in[5];
  const float* bv = (const float*)d_in[6];
  const float* Wo = (const float*)d_in[7];
  const float* bo = (const float*)d_in[8];
  const float* hp = (const float*)d_in[9];
  float* out = (float*)d_out;

  char* ws = (char*)d_ws;
  size_t off = 0;
  auto alloc = [&](size_t b) {
    char* p = ws + off;
    off += (b + 255) & ~(size_t)255;
    return p;
  };

  const int N = N_TOK, D = D_MODEL;
  u16* xhi    = (u16*)alloc((size_t)N * D * 2);
  u16* xlo    = (u16*)alloc((size_t)N * D * 2);
  u16* wqt_hi = (u16*)alloc((size_t)D * D * 2);
  u16* wqt_lo = (u16*)alloc((size_t)D * D * 2);
  u16* kvt    = (u16*)alloc((size_t)2 * D * D * 2);  // [Wk^T ; Wv^T]
  u16* wot    = (u16*)alloc((size_t)D * D * 2);
  float* Qf   = (float*)alloc((size_t)N * D * 4);
  u16* qbb    = (u16*)alloc((size_t)N * D * 2);
  u16* kbb    = (u16*)alloc((size_t)N * D * 2);
  u16* vtb    = (u16*)alloc((size_t)D * N * 2);
  int* bucket = (int*)alloc((size_t)N_HEAD * N * 4);
  float* Opart = (float*)alloc((size_t)SPLITS * N * D * 4);
  float* Mpart = (float*)alloc((size_t)SPLITS * N_HEAD * N * 4);
  float* Lpart = (float*)alloc((size_t)SPLITS * N_HEAD * N * 4);
  u16* ob     = (u16*)alloc((size_t)N * D * 2);

  const int nelem = N * D;
  dim3 tb(32, 8);

  split_cast_kernel<<<(nelem + 255) / 256, 256, 0, stream>>>(x, xhi, xlo, nelem);
  transpose_split_kernel<<<dim3(D / 32, D / 32), tb, 0, stream>>>(Wq, wqt_hi, wqt_lo, D, D);
  transpose_split_kernel<<<dim3(D / 32, D / 32), tb, 0, stream>>>(Wk, kvt, nullptr, D, D);
  transpose_split_kernel<<<dim3(D / 32, D / 32), tb, 0, stream>>>(Wv, kvt + (size_t)D * D, nullptr, D, D);
  transpose_split_kernel<<<dim3(D / 32, D / 32), tb, 0, stream>>>(Wo, wot, nullptr, D, D);

  // Q: fused hi/lo 3-pass, f32 Qf (for hash) + bf16 qbb
  gemm3_bf16_kernel<<<(N / 64) * (D / 128), 256, 0, stream>>>(
      xhi, xlo, wqt_hi, wqt_lo, Qf, bq, qbb, N, D, D);
  // K|V fused: bf16 kbb + transposed bf16 vtb
  gemm_bf16_kernel<128><<<(N / 128) * (2 * D / 128), 256, 0, stream>>>(
      xhi, kvt, nullptr, bk, bv, kbb, vtb, N, 2 * D, D, 2 | 8);

  hash_argmax_kernel<<<N, 512, 0, stream>>>(Qf, hp, bucket);

  attn_split_kernel<<<dim3(N / 64, N_HEAD, SPLITS), 256, 0, stream>>>(
      qbb, kbb, vtb, bucket, Opart, Mpart, Lpart);
  combine_kernel<<<(N * D / 4) / 256, 256, 0, stream>>>(Opart, Mpart, Lpart, ob);

  gemm_bf16_kernel<64><<<(N / 64) * (D / 128), 256, 0, stream>>>(
      ob, wot, out, bo, nullptr, nullptr, nullptr, N, D, D, 2);

  (void)in_sizes; (void)n_in; (void)out_size; (void)ws_size;
}

// Round 3
// 194.934 us; speedup vs baseline: 2.2294x; 1.4692x over previous
//
#include <hip/hip_runtime.h>
#include <stdint.h>

typedef __attribute__((ext_vector_type(8))) short short8;
typedef __attribute__((ext_vector_type(4))) short short4v;
typedef __attribute__((ext_vector_type(4))) float float4v;
typedef unsigned short u16;

#define N_TOK 2048
#define D_MODEL 1024
#define N_HEAD 8
#define HDIM 128
#define N_BUCKET 64
#define WL_CAP 2048
#define ATTN_BLOCKS 384  // 1536 wave slots >= worst-case worklist (8*(64+128))

__device__ __forceinline__ u16 f2bf(float f) {
  uint32_t u = __float_as_uint(f);
  uint32_t r = u + 0x7fffu + ((u >> 16) & 1u);
  return (u16)(r >> 16);
}
__device__ __forceinline__ float bf2f(u16 h) {
  return __uint_as_float(((uint32_t)h) << 16);
}

__device__ __forceinline__ void async_load16(const void* g, void* l) {
  __builtin_amdgcn_global_load_lds(
      (const __attribute__((address_space(1))) void*)g,
      (__attribute__((address_space(3))) void*)l, 16, 0, 0);
}

// ---------- elementwise f32 -> bf16 hi (+ optional lo residual) ----------
__global__ __launch_bounds__(256) void split_cast_kernel(
    const float* __restrict__ in, u16* __restrict__ hi, u16* __restrict__ lo,
    int n) {
  int i = blockIdx.x * 256 + threadIdx.x;
  if (i >= n) return;
  float v = in[i];
  u16 h = f2bf(v);
  hi[i] = h;
  if (lo) lo[i] = f2bf(v - bf2f(h));
}

// ---------- transpose + cast: in[R][C] f32 -> hi/lo [C][R] bf16 ----------
__global__ __launch_bounds__(256) void transpose_split_kernel(
    const float* __restrict__ in, u16* __restrict__ hi, u16* __restrict__ lo,
    int R, int C) {
  __shared__ float tile[32][33];
  int c0 = blockIdx.x * 32, r0 = blockIdx.y * 32;
  int tx = threadIdx.x, ty = threadIdx.y;  // 32 x 8
#pragma unroll
  for (int i = 0; i < 4; i++) {
    int rl = ty + i * 8;
    tile[rl][tx] = in[(size_t)(r0 + rl) * C + c0 + tx];
  }
  __syncthreads();
#pragma unroll
  for (int i = 0; i < 4; i++) {
    int cl = ty + i * 8;
    float v = tile[tx][cl];
    size_t oidx = (size_t)(c0 + cl) * R + r0 + tx;
    u16 h = f2bf(v);
    hi[oidx] = h;
    if (lo) lo[oidx] = f2bf(v - bf2f(h));
  }
}

// ---------- GEMM staging ----------
template <int BM>
__device__ __forceinline__ void stage_tiles(const u16* A, const u16* Bt,
                                            u16* As, u16* Bs, int bm, int bn,
                                            int K, int ko, int wave, int lane) {
  const int arow = lane >> 2;
  const int acolb = (lane & 3) * 16;
  constexpr int ACH = BM / 16;
  constexpr int PC = (ACH + 8) / 4;
#pragma unroll
  for (int cc = 0; cc < PC; cc++) {
    int idx = wave * PC + cc;
    if (idx < ACH) {
      int row = idx * 16 + arow;
      const char* g = (const char*)A + ((size_t)(bm + row) * K + ko) * 2 + acolb;
      async_load16(g, (char*)As + idx * 1024);
    } else {
      int row = (idx - ACH) * 16 + arow;
      const char* g = (const char*)Bt + ((size_t)(bn + row) * K + ko) * 2 + acolb;
      async_load16(g, (char*)Bs + (idx - ACH) * 1024);
    }
  }
}

// flags: 1 = accumulate into C, 2 = add bias,
//        8 = KV mode (col<1024 -> kbf; col>=1024 -> vbf; bias/bias2; no C)
template <int BM>
__global__ __launch_bounds__(256) void gemm_bf16_kernel(
    const u16* __restrict__ A, const u16* __restrict__ Bt,
    float* __restrict__ C, const float* __restrict__ bias,
    const float* __restrict__ bias2, u16* __restrict__ kbf,
    u16* __restrict__ vbf, int M, int N, int K, int flags) {
  constexpr int MI = BM / 32;
  __shared__ __align__(16) u16 As[BM * 32];
  __shared__ __align__(16) u16 Bs[128 * 32];
  const int tid = threadIdx.x;
  const int wave = tid >> 6, lane = tid & 63;
  const int lhi = lane >> 4, llo = lane & 15;
  const int nbn = N >> 7;
  const int bm = (blockIdx.x / nbn) * BM;
  const int bn = (blockIdx.x % nbn) << 7;
  const int wm = (BM == 128) ? (wave >> 1) * 64 : (wave & 1) * 32;
  const int wn = (BM == 128) ? (wave & 1) * 64 : (wave >> 1) * 64;

  float4v acc[MI][4];
#pragma unroll
  for (int mi = 0; mi < MI; mi++)
#pragma unroll
    for (int ni = 0; ni < 4; ni++)
#pragma unroll
      for (int r = 0; r < 4; r++) acc[mi][ni][r] = 0.f;

  for (int ko = 0; ko < K; ko += 32) {
    stage_tiles<BM>(A, Bt, As, Bs, bm, bn, K, ko, wave, lane);
    __syncthreads();
    short8 af[MI], bfr[4];
#pragma unroll
    for (int i = 0; i < MI; i++)
      af[i] = *(const short8*)&As[(wm + i * 16 + llo) * 32 + lhi * 8];
#pragma unroll
    for (int i = 0; i < 4; i++)
      bfr[i] = *(const short8*)&Bs[(wn + i * 16 + llo) * 32 + lhi * 8];
#pragma unroll
    for (int mi = 0; mi < MI; mi++)
#pragma unroll
      for (int ni = 0; ni < 4; ni++)
        acc[mi][ni] = __builtin_amdgcn_mfma_f32_16x16x32_bf16(af[mi], bfr[ni],
                                                              acc[mi][ni], 0, 0, 0);
    __syncthreads();
  }

#pragma unroll
  for (int mi = 0; mi < MI; mi++)
#pragma unroll
    for (int ni = 0; ni < 4; ni++) {
      int row0 = bm + wm + mi * 16 + lhi * 4;
      int col = bn + wn + ni * 16 + llo;
      if (flags & 8) {
        u16* dst = (col < 1024) ? kbf : vbf;
        int c = col & 1023;
        float bb = (col < 1024) ? bias[c] : bias2[c];
#pragma unroll
        for (int r = 0; r < 4; r++)
          dst[(size_t)(row0 + r) * 1024 + c] = f2bf(acc[mi][ni][r] + bb);
      } else {
        float bb = (flags & 2) ? bias[col] : 0.f;
        float* cp = C + (size_t)row0 * N + col;
#pragma unroll
        for (int r = 0; r < 4; r++) {
          float v = acc[mi][ni][r] + bb;
          if (flags & 1) v += cp[(size_t)r * N];
          cp[(size_t)r * N] = v;
        }
      }
    }
}

// ---------- fused 3-pass hi/lo GEMM for Q ----------
__global__ __launch_bounds__(256) void gemm3_bf16_kernel(
    const u16* __restrict__ A0, const u16* __restrict__ A1,
    const u16* __restrict__ B0, const u16* __restrict__ B1,
    float* __restrict__ C, const float* __restrict__ bias,
    u16* __restrict__ bf_out, int M, int N, int K) {
  constexpr int BM = 64;
  constexpr int MI = 2;
  __shared__ __align__(16) u16 As[BM * 32];
  __shared__ __align__(16) u16 Bs[128 * 32];
  const int tid = threadIdx.x;
  const int wave = tid >> 6, lane = tid & 63;
  const int lhi = lane >> 4, llo = lane & 15;
  const int nbn = N >> 7;
  const int bm = (blockIdx.x / nbn) * BM;
  const int bn = (blockIdx.x % nbn) << 7;
  const int wm = (wave & 1) * 32;
  const int wn = (wave >> 1) * 64;

  float4v acc[MI][4];
#pragma unroll
  for (int mi = 0; mi < MI; mi++)
#pragma unroll
    for (int ni = 0; ni < 4; ni++)
#pragma unroll
      for (int r = 0; r < 4; r++) acc[mi][ni][r] = 0.f;

  for (int kk = 0; kk < 3 * 1024; kk += 32) {
    int p = kk >> 10;
    int ko = kk & 1023;
    const u16* Ap = (p == 2) ? A1 : A0;
    const u16* Bp = (p == 1) ? B1 : B0;
    stage_tiles<BM>(Ap, Bp, As, Bs, bm, bn, K, ko, wave, lane);
    __syncthreads();
    short8 af[MI], bfr[4];
#pragma unroll
    for (int i = 0; i < MI; i++)
      af[i] = *(const short8*)&As[(wm + i * 16 + llo) * 32 + lhi * 8];
#pragma unroll
    for (int i = 0; i < 4; i++)
      bfr[i] = *(const short8*)&Bs[(wn + i * 16 + llo) * 32 + lhi * 8];
#pragma unroll
    for (int mi = 0; mi < MI; mi++)
#pragma unroll
      for (int ni = 0; ni < 4; ni++)
        acc[mi][ni] = __builtin_amdgcn_mfma_f32_16x16x32_bf16(af[mi], bfr[ni],
                                                              acc[mi][ni], 0, 0, 0);
    __syncthreads();
  }

#pragma unroll
  for (int mi = 0; mi < MI; mi++)
#pragma unroll
    for (int ni = 0; ni < 4; ni++) {
      int row0 = bm + wm + mi * 16 + lhi * 4;
      int col = bn + wn + ni * 16 + llo;
      float bb = bias[col];
#pragma unroll
      for (int r = 0; r < 4; r++) {
        float v = acc[mi][ni][r] + bb;
        C[(size_t)(row0 + r) * N + col] = v;
        bf_out[(size_t)(row0 + r) * N + col] = f2bf(v);
      }
    }
}

// ---------- hash scores + argmax -> bucket[H][N] ----------
__global__ __launch_bounds__(512) void hash_argmax_kernel(
    const float* __restrict__ Q, const float* __restrict__ proj,
    int* __restrict__ bucket) {
  int n = blockIdx.x;
  int hh = threadIdx.x >> 6;
  int f = threadIdx.x & 63;
  const float* qp = Q + (size_t)n * D_MODEL + hh * HDIM;
  const float* pp = proj + (size_t)hh * HDIM * N_BUCKET + f;
  float s = 0.f;
#pragma unroll 4
  for (int d = 0; d < HDIM; d++) s += qp[d] * pp[(size_t)d * N_BUCKET];
  int idx = f;
#pragma unroll
  for (int off = 32; off > 0; off >>= 1) {
    float ov = __shfl_xor(s, off);
    int oi = __shfl_xor(idx, off);
    if (ov > s || (ov == s && oi < idx)) { s = ov; idx = oi; }
  }
  if (f == 0) bucket[hh * N_TOK + n] = idx;
}

// ---------- bucket counts: one wave per (h,b) ----------
__global__ __launch_bounds__(64) void bucket_count_kernel(
    const int* __restrict__ bucket, int* __restrict__ counts) {
  int hb = blockIdx.x;  // h*64+b
  int h = hb >> 6, b = hb & 63;
  int lane = threadIdx.x;
  int cnt = 0;
  for (int t = 0; t < N_TOK; t += 64) {
    bool match = bucket[h * N_TOK + t + lane] == b;
    unsigned long long mask = __ballot(match);
    cnt += __popcll(mask);
  }
  if (lane == 0) counts[hb] = cnt;
}

// ---------- scans: global token offsets + worklist ----------
__global__ __launch_bounds__(512) void build_wl_kernel(
    const int* __restrict__ counts, int* __restrict__ offsets,
    int* __restrict__ wl, int* __restrict__ wl_count) {
  __shared__ int sc[512];
  int tid = threadIdx.x;
  int cnt = counts[tid];
  // scan 1: token offsets (global across h,b since layout is h-major)
  sc[tid] = cnt;
  __syncthreads();
  for (int o = 1; o < 512; o <<= 1) {
    int v = (tid >= o) ? sc[tid - o] : 0;
    __syncthreads();
    sc[tid] += v;
    __syncthreads();
  }
  offsets[tid] = sc[tid] - cnt;
  __syncthreads();
  // scan 2: worklist bases
  int nq = (cnt + 15) >> 4;
  sc[tid] = nq;
  __syncthreads();
  for (int o = 1; o < 512; o <<= 1) {
    int v = (tid >= o) ? sc[tid - o] : 0;
    __syncthreads();
    sc[tid] += v;
    __syncthreads();
  }
  int base = sc[tid] - nq;
  int h = tid >> 6, b = tid & 63;
  for (int i = 0; i < nq; i++) wl[base + i] = (h << 13) | (b << 7) | i;
  if (tid == 511) wl_count[0] = sc[511];
}

// ---------- stable fill of permutation ----------
__global__ __launch_bounds__(64) void bucket_fill_kernel(
    const int* __restrict__ bucket, const int* __restrict__ offsets,
    int* __restrict__ perm) {
  int hb = blockIdx.x;
  int h = hb >> 6, b = hb & 63;
  int lane = threadIdx.x;
  int base = offsets[hb];
  for (int t = 0; t < N_TOK; t += 64) {
    int tok = t + lane;
    bool match = bucket[h * N_TOK + tok] == b;
    unsigned long long mask = __ballot(match);
    if (match) {
      int pos = base + __popcll(mask & ((1ull << lane) - 1ull));
      perm[pos] = tok;
    }
    base += __popcll(mask);
  }
}

// ---------- gather-transpose V: Vts[h][d][pos] = vbb[perm[h*N+pos]][h*128+d] ----
__global__ __launch_bounds__(256) void gather_vt_kernel(
    const u16* __restrict__ vbb, const int* __restrict__ perm,
    u16* __restrict__ Vts) {
  __shared__ u16 lds[64][72];
  int bid = blockIdx.x;               // h*64 + ptile*2 + dtile
  int h = bid >> 6;
  int ptile = (bid & 63) >> 1;        // 32 tiles of 64 pos
  int d0 = (bid & 1) * 64;
  int pos0 = ptile * 64;
  int t = threadIdx.x;
#pragma unroll
  for (int i = 0; i < 2; i++) {
    int unit = t + 256 * i;           // 512 units
    int p = unit >> 3, seg = unit & 7;
    int tok = perm[h * N_TOK + pos0 + p];
    short8 v = *(const short8*)&vbb[(size_t)tok * D_MODEL + h * HDIM + d0 + seg * 8];
    *(short8*)&lds[p][seg * 8] = v;
  }
  __syncthreads();
#pragma unroll
  for (int i = 0; i < 8; i++) {
    int unit = t + 256 * i;           // 2048 units
    int drow = unit >> 5, pp = unit & 31;
    uint32_t val = (uint32_t)lds[2 * pp][drow] |
                   ((uint32_t)lds[2 * pp + 1][drow] << 16);
    uint32_t* dst = (uint32_t*)&Vts[(size_t)(h * HDIM + d0 + drow) * N_TOK + pos0];
    dst[pp] = val;
  }
}

// ---------- per-bucket attention over sorted segments ----------
__global__ __launch_bounds__(256) void attn_bucket_kernel(
    const u16* __restrict__ qbb, const u16* __restrict__ kbb,
    const u16* __restrict__ Vts, const int* __restrict__ perm,
    const int* __restrict__ offsets, const int* __restrict__ counts,
    const int* __restrict__ wl, const int* __restrict__ wl_count,
    u16* __restrict__ ob) {
  const int wave = threadIdx.x >> 6, lane = threadIdx.x & 63;
  const int lhi = lane >> 4, llo = lane & 15;
  const int wslot = blockIdx.x * 4 + wave;
  const int NW = ATTN_BLOCKS * 4;
  const int cnt = wl_count[0];
  __shared__ __align__(16) u16 P_lds[4][16][64];
  const float scale = 0.08838834764831845f;  // 1/sqrt(128)

  for (int e = wslot; e < cnt; e += NW) {
    int ent = wl[e];
    int h = ent >> 13, hb = (ent >> 7) & 511, qt = ent & 127;
    hb = (h << 6) | ((ent >> 7) & 63);
    int off = offsets[hb];
    int bs = counts[hb];
    int offh = off - h * N_TOK;       // column within this head's Vts
    int qbase = qt * 16;

    // Q fragments (rows = llo), clamp padded rows
    int qr = qbase + llo;
    int tokq = perm[off + min(qr, bs - 1)];
    const u16* qrow = &qbb[(size_t)tokq * D_MODEL + h * HDIM];
    short8 qf[4];
#pragma unroll
    for (int kf = 0; kf < 4; kf++)
      qf[kf] = *(const short8*)&qrow[kf * 32 + lhi * 8];

    float m[4], l[4];
#pragma unroll
    for (int r = 0; r < 4; r++) { m[r] = -INFINITY; l[r] = 0.f; }
    float4v accO[8];
#pragma unroll
    for (int d = 0; d < 8; d++)
#pragma unroll
      for (int r = 0; r < 4; r++) accO[d][r] = 0.f;

    for (int c0 = 0; c0 < bs; c0 += 64) {
      float4v sc[4];
#pragma unroll
      for (int nf = 0; nf < 4; nf++)
#pragma unroll
        for (int r = 0; r < 4; r++) sc[nf][r] = 0.f;
#pragma unroll
      for (int nf = 0; nf < 4; nf++) {
        int kcol = c0 + nf * 16 + llo;
        int tokk = perm[off + min(kcol, bs - 1)];
        const u16* krow = &kbb[(size_t)tokk * D_MODEL + h * HDIM];
#pragma unroll
        for (int kf = 0; kf < 4; kf++) {
          short8 kfr = *(const short8*)&krow[kf * 32 + lhi * 8];
          sc[nf] = __builtin_amdgcn_mfma_f32_16x16x32_bf16(qf[kf], kfr, sc[nf], 0, 0, 0);
        }
      }

      float tmax[4];
#pragma unroll
      for (int r = 0; r < 4; r++) tmax[r] = -INFINITY;
#pragma unroll
      for (int nf = 0; nf < 4; nf++) {
        bool valid = (c0 + nf * 16 + llo) < bs;
#pragma unroll
        for (int r = 0; r < 4; r++) {
          float v = valid ? sc[nf][r] * scale : -1e30f;
          sc[nf][r] = v;
          tmax[r] = fmaxf(tmax[r], v);
        }
      }
#pragma unroll
      for (int r = 0; r < 4; r++)
#pragma unroll
        for (int o = 1; o < 16; o <<= 1)
          tmax[r] = fmaxf(tmax[r], __shfl_xor(tmax[r], o));

      float resc[4], psum[4];
#pragma unroll
      for (int r = 0; r < 4; r++) {
        float mn = fmaxf(m[r], tmax[r]);
        resc[r] = __expf(m[r] - mn);
        m[r] = mn;
        psum[r] = 0.f;
      }
#pragma unroll
      for (int nf = 0; nf < 4; nf++)
#pragma unroll
        for (int r = 0; r < 4; r++) {
          float p = __expf(sc[nf][r] - m[r]);
          psum[r] += p;
          P_lds[wave][lhi * 4 + r][nf * 16 + llo] = f2bf(p);
        }
#pragma unroll
      for (int r = 0; r < 4; r++) {
#pragma unroll
        for (int o = 1; o < 16; o <<= 1) psum[r] += __shfl_xor(psum[r], o);
        l[r] = l[r] * resc[r] + psum[r];
      }
#pragma unroll
      for (int d = 0; d < 8; d++)
#pragma unroll
        for (int r = 0; r < 4; r++) accO[d][r] *= resc[r];

      asm volatile("s_waitcnt lgkmcnt(0)" ::: "memory");
      short8 pf[2];
#pragma unroll
      for (int k2 = 0; k2 < 2; k2++)
        pf[k2] = *(const short8*)&P_lds[wave][llo][k2 * 32 + lhi * 8];
#pragma unroll
      for (int d = 0; d < 8; d++)
#pragma unroll
        for (int k2 = 0; k2 < 2; k2++) {
          short8 vfr = *(const short8*)&Vts[(size_t)(h * HDIM + d * 16 + llo) * N_TOK +
                                            offh + c0 + k2 * 32 + lhi * 8];
          accO[d] = __builtin_amdgcn_mfma_f32_16x16x32_bf16(pf[k2], vfr, accO[d], 0, 0, 0);
        }
      asm volatile("" ::: "memory");
    }

#pragma unroll
    for (int r = 0; r < 4; r++) {
      int rl = qbase + lhi * 4 + r;
      if (rl < bs) {
        int tok = perm[off + rl];
        float inv = 1.f / l[r];
#pragma unroll
        for (int d = 0; d < 8; d++)
          ob[(size_t)tok * D_MODEL + h * HDIM + d * 16 + llo] = f2bf(accO[d][r] * inv);
      }
    }
  }
}

extern "C" void kernel_launch(void* const* d_in, const int* in_sizes, int n_in,
                              void* d_out, int out_size, void* d_ws, size_t ws_size,
                              hipStream_t stream) {
  const float* x  = (const float*)d_in[0];
  const float* Wq = (const float*)d_in[1];
  const float* bq = (const float*)d_in[2];
  const float* Wk = (const float*)d_in[3];
  const float* bk = (const float*)d_in[4];
  const float* Wv = (const float*)d_in[5];
  const float* bv = (const float*)d_in[6];
  const float* Wo = (const float*)d_in[7];
  const float* bo = (const float*)d_in[8];
  const float* hp = (const float*)d_in[9];
  float* out = (float*)d_out;

  char* ws = (char*)d_ws;
  size_t off = 0;
  auto alloc = [&](size_t b) {
    char* p = ws + off;
    off += (b + 255) & ~(size_t)255;
    return p;
  };

  const int N = N_TOK, D = D_MODEL;
  u16* xhi    = (u16*)alloc((size_t)N * D * 2);
  u16* xlo    = (u16*)alloc((size_t)N * D * 2);
  u16* wqt_hi = (u16*)alloc((size_t)D * D * 2);
  u16* wqt_lo = (u16*)alloc((size_t)D * D * 2);
  u16* kvt    = (u16*)alloc((size_t)2 * D * D * 2);
  u16* wot    = (u16*)alloc((size_t)D * D * 2);
  float* Qf   = (float*)alloc((size_t)N * D * 4);
  u16* qbb    = (u16*)alloc((size_t)N * D * 2);
  u16* kbb    = (u16*)alloc((size_t)N * D * 2);
  u16* vbb    = (u16*)alloc((size_t)N * D * 2);
  u16* Vts    = (u16*)alloc((size_t)N_HEAD * HDIM * N * 2 + 256);  // +tail pad
  int* bucket = (int*)alloc((size_t)N_HEAD * N * 4);
  int* counts = (int*)alloc(512 * 4);
  int* offs   = (int*)alloc(512 * 4);
  int* perm   = (int*)alloc((size_t)N_HEAD * N * 4);
  int* wl     = (int*)alloc(WL_CAP * 4);
  int* wlcnt  = (int*)alloc(256);
  u16* ob     = (u16*)alloc((size_t)N * D * 2);

  const int nelem = N * D;
  dim3 tb(32, 8);

  split_cast_kernel<<<(nelem + 255) / 256, 256, 0, stream>>>(x, xhi, xlo, nelem);
  transpose_split_kernel<<<dim3(D / 32, D / 32), tb, 0, stream>>>(Wq, wqt_hi, wqt_lo, D, D);
  transpose_split_kernel<<<dim3(D / 32, D / 32), tb, 0, stream>>>(Wk, kvt, nullptr, D, D);
  transpose_split_kernel<<<dim3(D / 32, D / 32), tb, 0, stream>>>(Wv, kvt + (size_t)D * D, nullptr, D, D);
  transpose_split_kernel<<<dim3(D / 32, D / 32), tb, 0, stream>>>(Wo, wot, nullptr, D, D);

  gemm3_bf16_kernel<<<(N / 64) * (D / 128), 256, 0, stream>>>(
      xhi, xlo, wqt_hi, wqt_lo, Qf, bq, qbb, N, D, D);
  gemm_bf16_kernel<128><<<(N / 128) * (2 * D / 128), 256, 0, stream>>>(
      xhi, kvt, nullptr, bk, bv, kbb, vbb, N, 2 * D, D, 2 | 8);

  hash_argmax_kernel<<<N, 512, 0, stream>>>(Qf, hp, bucket);
  bucket_count_kernel<<<512, 64, 0, stream>>>(bucket, counts);
  build_wl_kernel<<<1, 512, 0, stream>>>(counts, offs, wl, wlcnt);
  bucket_fill_kernel<<<512, 64, 0, stream>>>(bucket, offs, perm);
  gather_vt_kernel<<<512, 256, 0, stream>>>(vbb, perm, Vts);

  attn_bucket_kernel<<<ATTN_BLOCKS, 256, 0, stream>>>(
      qbb, kbb, Vts, perm, offs, counts, wl, wlcnt, ob);

  gemm_bf16_kernel<64><<<(N / 64) * (D / 128), 256, 0, stream>>>(
      ob, wot, out, bo, nullptr, nullptr, nullptr, N, D, D, 2);

  (void)in_sizes; (void)n_in; (void)out_size; (void)ws_size;
}

// Round 4
// 131.660 us; speedup vs baseline: 3.3008x; 1.4806x over previous
//
#include <hip/hip_runtime.h>
#include <stdint.h>

typedef __attribute__((ext_vector_type(8))) short short8;
typedef __attribute__((ext_vector_type(4))) short short4v;
typedef __attribute__((ext_vector_type(4))) float float4v;
typedef unsigned short u16;

#define N_TOK 2048
#define D_MODEL 1024
#define N_HEAD 8
#define HDIM 128
#define N_BUCKET 64
#define WL_CAP 2048
#define ATTN_BLOCKS 384

__device__ __forceinline__ u16 f2bf(float f) {
  uint32_t u = __float_as_uint(f);
  uint32_t r = u + 0x7fffu + ((u >> 16) & 1u);
  return (u16)(r >> 16);
}
__device__ __forceinline__ float bf2f(u16 h) {
  return __uint_as_float(((uint32_t)h) << 16);
}

__device__ __forceinline__ void async_load16(const void* g, void* l) {
  __builtin_amdgcn_global_load_lds(
      (const __attribute__((address_space(1))) void*)g,
      (__attribute__((address_space(3))) void*)l, 16, 0, 0);
}

__device__ __forceinline__ int xcd_swz(int bid, int nwg) {
  // nwg must be a multiple of 8 (all our grids are)
  return (bid & 7) * (nwg >> 3) + (bid >> 3);
}

// ---------- elementwise f32 -> bf16 hi + lo residual ----------
__global__ __launch_bounds__(256) void split_cast_kernel(
    const float* __restrict__ in, u16* __restrict__ hi, u16* __restrict__ lo,
    int n) {
  int i = blockIdx.x * 256 + threadIdx.x;
  if (i >= n) return;
  float v = in[i];
  u16 h = f2bf(v);
  hi[i] = h;
  if (lo) lo[i] = f2bf(v - bf2f(h));
}

// ---------- fused transpose of all 4 weight matrices ----------
__global__ __launch_bounds__(256) void transpose_all_kernel(
    const float* __restrict__ Wq, const float* __restrict__ Wk,
    const float* __restrict__ Wv, const float* __restrict__ Wo,
    u16* __restrict__ wqt_hi, u16* __restrict__ wqt_lo,
    u16* __restrict__ kvt, u16* __restrict__ wot) {
  __shared__ float tile[32][33];
  const int z = blockIdx.z;
  const float* in = (z == 0) ? Wq : (z == 1) ? Wk : (z == 2) ? Wv : Wo;
  u16* hi = (z == 0) ? wqt_hi
            : (z == 1) ? kvt
            : (z == 2) ? (kvt + (size_t)1024 * 1024) : wot;
  u16* lo = (z == 0) ? wqt_lo : nullptr;
  const int C = 1024, R = 1024;
  int c0 = blockIdx.x * 32, r0 = blockIdx.y * 32;
  int tx = threadIdx.x & 31, ty = threadIdx.x >> 5;  // 32 x 8
#pragma unroll
  for (int i = 0; i < 4; i++) {
    int rl = ty + i * 8;
    tile[rl][tx] = in[(size_t)(r0 + rl) * C + c0 + tx];
  }
  __syncthreads();
#pragma unroll
  for (int i = 0; i < 4; i++) {
    int cl = ty + i * 8;
    float v = tile[tx][cl];
    size_t oidx = (size_t)(c0 + cl) * R + r0 + tx;
    u16 h = f2bf(v);
    hi[oidx] = h;
    if (lo) lo[oidx] = f2bf(v - bf2f(h));
  }
}

// ---------- generic GEMM (BM x 128 tile, BK=32, dbuf prefetch) ----------
template <int BM>
__device__ __forceinline__ void stage_tiles2(const u16* A, const u16* Bt,
                                             u16* As, u16* Bs, int bm, int bn,
                                             int K, int ko, int wave, int lane) {
  const int arow = lane >> 2;
  const int acolb = (lane & 3) * 16;
  constexpr int ACH = BM / 16;
  constexpr int PC = (ACH + 8) / 4;
#pragma unroll
  for (int cc = 0; cc < PC; cc++) {
    int idx = wave * PC + cc;
    if (idx < ACH) {
      int row = idx * 16 + arow;
      const char* g = (const char*)A + ((size_t)(bm + row) * K + ko) * 2 + acolb;
      async_load16(g, (char*)As + idx * 1024);
    } else {
      int row = (idx - ACH) * 16 + arow;
      const char* g = (const char*)Bt + ((size_t)(bn + row) * K + ko) * 2 + acolb;
      async_load16(g, (char*)Bs + (idx - ACH) * 1024);
    }
  }
}

// flags: 2 = add bias, 8 = KV mode (col<1024 -> kbf; col>=1024 -> vbf)
template <int BM>
__global__ __launch_bounds__(256) void gemm_bf16_kernel(
    const u16* __restrict__ A, const u16* __restrict__ Bt,
    float* __restrict__ C, const float* __restrict__ bias,
    const float* __restrict__ bias2, u16* __restrict__ kbf,
    u16* __restrict__ vbf, int N, int K, int flags) {
  constexpr int MI = BM / 32;
  __shared__ __align__(16) u16 As[2][BM * 32];
  __shared__ __align__(16) u16 Bs[2][128 * 32];
  const int tid = threadIdx.x;
  const int wave = tid >> 6, lane = tid & 63;
  const int lhi = lane >> 4, llo = lane & 15;
  const int nbn = N >> 7;
  const int bid = xcd_swz(blockIdx.x, gridDim.x);
  const int bm = (bid / nbn) * BM;
  const int bn = (bid % nbn) << 7;
  const int wm = (BM == 128) ? (wave >> 1) * 64 : (wave & 1) * 32;
  const int wn = (BM == 128) ? (wave & 1) * 64 : (wave >> 1) * 64;

  float4v acc[MI][4];
#pragma unroll
  for (int mi = 0; mi < MI; mi++)
#pragma unroll
    for (int ni = 0; ni < 4; ni++)
#pragma unroll
      for (int r = 0; r < 4; r++) acc[mi][ni][r] = 0.f;

  stage_tiles2<BM>(A, Bt, As[0], Bs[0], bm, bn, K, 0, wave, lane);
  __syncthreads();
  const int nk = K >> 5;
  for (int t = 0; t < nk; t++) {
    const int cur = t & 1;
    if (t + 1 < nk)
      stage_tiles2<BM>(A, Bt, As[cur ^ 1], Bs[cur ^ 1], bm, bn, K,
                       (t + 1) << 5, wave, lane);
    short8 af[MI], bfr[4];
#pragma unroll
    for (int i = 0; i < MI; i++)
      af[i] = *(const short8*)&As[cur][(wm + i * 16 + llo) * 32 + lhi * 8];
#pragma unroll
    for (int i = 0; i < 4; i++)
      bfr[i] = *(const short8*)&Bs[cur][(wn + i * 16 + llo) * 32 + lhi * 8];
#pragma unroll
    for (int mi = 0; mi < MI; mi++)
#pragma unroll
      for (int ni = 0; ni < 4; ni++)
        acc[mi][ni] = __builtin_amdgcn_mfma_f32_16x16x32_bf16(af[mi], bfr[ni],
                                                              acc[mi][ni], 0, 0, 0);
    __syncthreads();
  }

#pragma unroll
  for (int mi = 0; mi < MI; mi++)
#pragma unroll
    for (int ni = 0; ni < 4; ni++) {
      int row0 = bm + wm + mi * 16 + lhi * 4;
      int col = bn + wn + ni * 16 + llo;
      if (flags & 8) {
        u16* dst = (col < 1024) ? kbf : vbf;
        int c = col & 1023;
        float bb = (col < 1024) ? bias[c] : bias2[c];
#pragma unroll
        for (int r = 0; r < 4; r++)
          dst[(size_t)(row0 + r) * 1024 + c] = f2bf(acc[mi][ni][r] + bb);
      } else {
        float bb = (flags & 2) ? bias[col] : 0.f;
        float* cp = C + (size_t)row0 * N + col;
#pragma unroll
        for (int r = 0; r < 4; r++) cp[(size_t)r * N] = acc[mi][ni][r] + bb;
      }
    }
}

// ---------- Q GEMM: interleaved hi/lo compensated, single K-walk ----------
// acc = A_hi*B_hi + A_hi*B_lo + A_lo*B_hi  (+bias) -> Qf f32 + qbb bf16
__global__ __launch_bounds__(256) void gemm3_bf16_kernel(
    const u16* __restrict__ A0, const u16* __restrict__ A1,
    const u16* __restrict__ B0, const u16* __restrict__ B1,
    float* __restrict__ C, const float* __restrict__ bias,
    u16* __restrict__ bf_out, int N, int K) {
  constexpr int MI = 2;  // BM=64, BN=128
  // per-buf layout (u16 idx): Ah 0..2048, Al 2048..4096, Bh 4096..8192, Bl 8192..12288
  __shared__ __align__(16) u16 S3[2][12288];
  const int tid = threadIdx.x;
  const int wave = tid >> 6, lane = tid & 63;
  const int lhi = lane >> 4, llo = lane & 15;
  const int nbn = N >> 7;
  const int bid = xcd_swz(blockIdx.x, gridDim.x);
  const int bm = (bid / nbn) * 64;
  const int bn = (bid % nbn) << 7;
  const int wm = (wave & 1) * 32;
  const int wn = (wave >> 1) * 64;
  const int arow = lane >> 2;
  const int acolb = (lane & 3) * 16;

  float4v acc[MI][4];
#pragma unroll
  for (int mi = 0; mi < MI; mi++)
#pragma unroll
    for (int ni = 0; ni < 4; ni++)
#pragma unroll
      for (int r = 0; r < 4; r++) acc[mi][ni][r] = 0.f;

  auto stage = [&](int b, int ko) {
    char* base = (char*)&S3[b][0];
#pragma unroll
    for (int cc = 0; cc < 6; cc++) {
      int idx = wave * 6 + cc;  // 0..23
      const u16* src;
      int row;
      char* dst;
      if (idx < 4) {
        src = A0; row = bm + idx * 16 + arow; dst = base + idx * 1024;
      } else if (idx < 8) {
        src = A1; row = bm + (idx - 4) * 16 + arow; dst = base + 4096 + (idx - 4) * 1024;
      } else if (idx < 16) {
        src = B0; row = bn + (idx - 8) * 16 + arow; dst = base + 8192 + (idx - 8) * 1024;
      } else {
        src = B1; row = bn + (idx - 16) * 16 + arow; dst = base + 16384 + (idx - 16) * 1024;
      }
      async_load16((const char*)src + ((size_t)row * K + ko) * 2 + acolb, dst);
    }
  };

  stage(0, 0);
  __syncthreads();
  const int nk = K >> 5;
  for (int t = 0; t < nk; t++) {
    const int cur = t & 1;
    if (t + 1 < nk) stage(cur ^ 1, (t + 1) << 5);
    const u16* Sc = &S3[cur][0];
    short8 afh[MI], afl[MI], bfh[4], bfl[4];
#pragma unroll
    for (int i = 0; i < MI; i++) {
      afh[i] = *(const short8*)&Sc[(wm + i * 16 + llo) * 32 + lhi * 8];
      afl[i] = *(const short8*)&Sc[2048 + (wm + i * 16 + llo) * 32 + lhi * 8];
    }
#pragma unroll
    for (int i = 0; i < 4; i++) {
      bfh[i] = *(const short8*)&Sc[4096 + (wn + i * 16 + llo) * 32 + lhi * 8];
      bfl[i] = *(const short8*)&Sc[8192 + (wn + i * 16 + llo) * 32 + lhi * 8];
    }
#pragma unroll
    for (int mi = 0; mi < MI; mi++)
#pragma unroll
      for (int ni = 0; ni < 4; ni++)
        acc[mi][ni] = __builtin_amdgcn_mfma_f32_16x16x32_bf16(afh[mi], bfh[ni],
                                                              acc[mi][ni], 0, 0, 0);
#pragma unroll
    for (int mi = 0; mi < MI; mi++)
#pragma unroll
      for (int ni = 0; ni < 4; ni++)
        acc[mi][ni] = __builtin_amdgcn_mfma_f32_16x16x32_bf16(afh[mi], bfl[ni],
                                                              acc[mi][ni], 0, 0, 0);
#pragma unroll
    for (int mi = 0; mi < MI; mi++)
#pragma unroll
      for (int ni = 0; ni < 4; ni++)
        acc[mi][ni] = __builtin_amdgcn_mfma_f32_16x16x32_bf16(afl[mi], bfh[ni],
                                                              acc[mi][ni], 0, 0, 0);
    __syncthreads();
  }

#pragma unroll
  for (int mi = 0; mi < MI; mi++)
#pragma unroll
    for (int ni = 0; ni < 4; ni++) {
      int row0 = bm + wm + mi * 16 + lhi * 4;
      int col = bn + wn + ni * 16 + llo;
      float bb = bias[col];
#pragma unroll
      for (int r = 0; r < 4; r++) {
        float v = acc[mi][ni][r] + bb;
        C[(size_t)(row0 + r) * N + col] = v;
        bf_out[(size_t)(row0 + r) * N + col] = f2bf(v);
      }
    }
}

// ---------- hash scores + argmax (LDS-tiled) ----------
// grid (N/64, H), 256 threads; sQ swizzled in 16B blocks to kill bank conflicts
__global__ __launch_bounds__(256) void hash_argmax_kernel(
    const float* __restrict__ Qf, const float* __restrict__ proj,
    int* __restrict__ bucket) {
  __shared__ float sQ[64 * 128];   // 32 KB
  __shared__ float sP[128 * 64];   // 32 KB
  const int tid = threadIdx.x;
  const int h = blockIdx.y;
  const int n0 = blockIdx.x * 64;
#pragma unroll
  for (int p = 0; p < 8; p++) {
    int e = p * 1024 + tid * 4;
    int tok = e >> 7, d0 = e & 127;
    float4v v = *(const float4v*)&Qf[(size_t)(n0 + tok) * D_MODEL + h * HDIM + d0];
    int blk = (d0 >> 2) ^ ((tok >> 2) & 7);
    *(float4v*)&sQ[tok * 128 + blk * 4] = v;
  }
#pragma unroll
  for (int p = 0; p < 8; p++) {
    int e = p * 1024 + tid * 4;
    float4v v = *(const float4v*)&proj[(size_t)h * (HDIM * N_BUCKET) + e];
    *(float4v*)&sP[e] = v;
  }
  __syncthreads();

  const int tgrp = tid & 15, fgrp = tid >> 4;
  const int t0 = tgrp * 4, f0 = fgrp * 4;
  float accs[4][4];
#pragma unroll
  for (int i = 0; i < 4; i++)
#pragma unroll
    for (int f = 0; f < 4; f++) accs[i][f] = 0.f;

  for (int d0 = 0; d0 < 128; d0 += 4) {
    int blk = (d0 >> 2) ^ (tgrp & 7);
    float4v qv[4], pv[4];
#pragma unroll
    for (int i = 0; i < 4; i++)
      qv[i] = *(const float4v*)&sQ[(t0 + i) * 128 + blk * 4];
#pragma unroll
    for (int j = 0; j < 4; j++)
      pv[j] = *(const float4v*)&sP[(d0 + j) * 64 + f0];
#pragma unroll
    for (int i = 0; i < 4; i++)
#pragma unroll
      for (int f = 0; f < 4; f++)
        accs[i][f] += qv[i][0] * pv[0][f] + qv[i][1] * pv[1][f] +
                      qv[i][2] * pv[2][f] + qv[i][3] * pv[3][f];
  }

  __syncthreads();
  float* vals = sQ;                       // [64][17]
  int* idxs = (int*)(sQ + 64 * 17);       // [64][17]
#pragma unroll
  for (int i = 0; i < 4; i++) {
    float bv = accs[i][0];
    int bi = f0;
#pragma unroll
    for (int f = 1; f < 4; f++)
      if (accs[i][f] > bv) { bv = accs[i][f]; bi = f0 + f; }
    vals[(t0 + i) * 17 + fgrp] = bv;
    idxs[(t0 + i) * 17 + fgrp] = bi;
  }
  __syncthreads();
  if (tid < 64) {
    float bv = vals[tid * 17];
    int bi = idxs[tid * 17];
#pragma unroll
    for (int g = 1; g < 16; g++) {
      float v = vals[tid * 17 + g];
      int id = idxs[tid * 17 + g];
      if (v > bv || (v == bv && id < bi)) { bv = v; bi = id; }
    }
    bucket[h * N_TOK + n0 + tid] = bi;
  }
}

// ---------- bucket counts ----------
__global__ __launch_bounds__(64) void bucket_count_kernel(
    const int* __restrict__ bucket, int* __restrict__ counts) {
  int hb = blockIdx.x;
  int h = hb >> 6, b = hb & 63;
  int lane = threadIdx.x;
  int cnt = 0;
  for (int t = 0; t < N_TOK; t += 64) {
    bool match = bucket[h * N_TOK + t + lane] == b;
    unsigned long long mask = __ballot(match);
    cnt += __popcll(mask);
  }
  if (lane == 0) counts[hb] = cnt;
}

// ---------- scans: offsets + worklist ----------
__global__ __launch_bounds__(512) void build_wl_kernel(
    const int* __restrict__ counts, int* __restrict__ offsets,
    int* __restrict__ wl, int* __restrict__ wl_count) {
  __shared__ int sc[512];
  int tid = threadIdx.x;
  int cnt = counts[tid];
  sc[tid] = cnt;
  __syncthreads();
  for (int o = 1; o < 512; o <<= 1) {
    int v = (tid >= o) ? sc[tid - o] : 0;
    __syncthreads();
    sc[tid] += v;
    __syncthreads();
  }
  offsets[tid] = sc[tid] - cnt;
  __syncthreads();
  int nq = (cnt + 15) >> 4;
  sc[tid] = nq;
  __syncthreads();
  for (int o = 1; o < 512; o <<= 1) {
    int v = (tid >= o) ? sc[tid - o] : 0;
    __syncthreads();
    sc[tid] += v;
    __syncthreads();
  }
  int base = sc[tid] - nq;
  int h = tid >> 6, b = tid & 63;
  for (int i = 0; i < nq; i++) wl[base + i] = (h << 13) | (b << 7) | i;
  if (tid == 511) wl_count[0] = sc[511];
}

// ---------- stable permutation fill ----------
__global__ __launch_bounds__(64) void bucket_fill_kernel(
    const int* __restrict__ bucket, const int* __restrict__ offsets,
    int* __restrict__ perm) {
  int hb = blockIdx.x;
  int h = hb >> 6, b = hb & 63;
  int lane = threadIdx.x;
  int base = offsets[hb];
  for (int t = 0; t < N_TOK; t += 64) {
    int tok = t + lane;
    bool match = bucket[h * N_TOK + tok] == b;
    unsigned long long mask = __ballot(match);
    if (match) {
      int pos = base + __popcll(mask & ((1ull << lane) - 1ull));
      perm[pos] = tok;
    }
    base += __popcll(mask);
  }
}

// ---------- gather-transpose V ----------
__global__ __launch_bounds__(256) void gather_vt_kernel(
    const u16* __restrict__ vbb, const int* __restrict__ perm,
    u16* __restrict__ Vts) {
  __shared__ u16 lds[64][72];
  int bid = blockIdx.x;
  int h = bid >> 6;
  int ptile = (bid & 63) >> 1;
  int d0 = (bid & 1) * 64;
  int pos0 = ptile * 64;
  int t = threadIdx.x;
#pragma unroll
  for (int i = 0; i < 2; i++) {
    int unit = t + 256 * i;
    int p = unit >> 3, seg = unit & 7;
    int tok = perm[h * N_TOK + pos0 + p];
    short8 v = *(const short8*)&vbb[(size_t)tok * D_MODEL + h * HDIM + d0 + seg * 8];
    *(short8*)&lds[p][seg * 8] = v;
  }
  __syncthreads();
#pragma unroll
  for (int i = 0; i < 8; i++) {
    int unit = t + 256 * i;
    int drow = unit >> 5, pp = unit & 31;
    uint32_t val = (uint32_t)lds[2 * pp][drow] |
                   ((uint32_t)lds[2 * pp + 1][drow] << 16);
    uint32_t* dst = (uint32_t*)&Vts[(size_t)(h * HDIM + d0 + drow) * N_TOK + pos0];
    dst[pp] = val;
  }
}

// ---------- per-bucket attention ----------
__global__ __launch_bounds__(256) void attn_bucket_kernel(
    const u16* __restrict__ qbb, const u16* __restrict__ kbb,
    const u16* __restrict__ Vts, const int* __restrict__ perm,
    const int* __restrict__ offsets, const int* __restrict__ counts,
    const int* __restrict__ wl, const int* __restrict__ wl_count,
    u16* __restrict__ ob) {
  const int wave = threadIdx.x >> 6, lane = threadIdx.x & 63;
  const int lhi = lane >> 4, llo = lane & 15;
  const int wslot = blockIdx.x * 4 + wave;
  const int NW = ATTN_BLOCKS * 4;
  const int cnt = wl_count[0];
  __shared__ __align__(16) u16 P_lds[4][16][64];
  const float scale = 0.08838834764831845f;

  for (int e = wslot; e < cnt; e += NW) {
    int ent = wl[e];
    int h = ent >> 13, qt = ent & 127;
    int hb = (h << 6) | ((ent >> 7) & 63);
    int off = offsets[hb];
    int bs = counts[hb];
    int offh = off - h * N_TOK;
    int qbase = qt * 16;

    int qr = qbase + llo;
    int tokq = perm[off + min(qr, bs - 1)];
    const u16* qrow = &qbb[(size_t)tokq * D_MODEL + h * HDIM];
    short8 qf[4];
#pragma unroll
    for (int kf = 0; kf < 4; kf++)
      qf[kf] = *(const short8*)&qrow[kf * 32 + lhi * 8];

    float m[4], l[4];
#pragma unroll
    for (int r = 0; r < 4; r++) { m[r] = -INFINITY; l[r] = 0.f; }
    float4v accO[8];
#pragma unroll
    for (int d = 0; d < 8; d++)
#pragma unroll
      for (int r = 0; r < 4; r++) accO[d][r] = 0.f;

    for (int c0 = 0; c0 < bs; c0 += 64) {
      float4v sc[4];
#pragma unroll
      for (int nf = 0; nf < 4; nf++)
#pragma unroll
        for (int r = 0; r < 4; r++) sc[nf][r] = 0.f;
#pragma unroll
      for (int nf = 0; nf < 4; nf++) {
        int kcol = c0 + nf * 16 + llo;
        int tokk = perm[off + min(kcol, bs - 1)];
        const u16* krow = &kbb[(size_t)tokk * D_MODEL + h * HDIM];
#pragma unroll
        for (int kf = 0; kf < 4; kf++) {
          short8 kfr = *(const short8*)&krow[kf * 32 + lhi * 8];
          sc[nf] = __builtin_amdgcn_mfma_f32_16x16x32_bf16(qf[kf], kfr, sc[nf], 0, 0, 0);
        }
      }

      float tmax[4];
#pragma unroll
      for (int r = 0; r < 4; r++) tmax[r] = -INFINITY;
#pragma unroll
      for (int nf = 0; nf < 4; nf++) {
        bool valid = (c0 + nf * 16 + llo) < bs;
#pragma unroll
        for (int r = 0; r < 4; r++) {
          float v = valid ? sc[nf][r] * scale : -1e30f;
          sc[nf][r] = v;
          tmax[r] = fmaxf(tmax[r], v);
        }
      }
#pragma unroll
      for (int r = 0; r < 4; r++)
#pragma unroll
        for (int o = 1; o < 16; o <<= 1)
          tmax[r] = fmaxf(tmax[r], __shfl_xor(tmax[r], o));

      float resc[4], psum[4];
#pragma unroll
      for (int r = 0; r < 4; r++) {
        float mn = fmaxf(m[r], tmax[r]);
        resc[r] = __expf(m[r] - mn);
        m[r] = mn;
        psum[r] = 0.f;
      }
#pragma unroll
      for (int nf = 0; nf < 4; nf++)
#pragma unroll
        for (int r = 0; r < 4; r++) {
          float p = __expf(sc[nf][r] - m[r]);
          psum[r] += p;
          P_lds[wave][lhi * 4 + r][nf * 16 + llo] = f2bf(p);
        }
#pragma unroll
      for (int r = 0; r < 4; r++) {
#pragma unroll
        for (int o = 1; o < 16; o <<= 1) psum[r] += __shfl_xor(psum[r], o);
        l[r] = l[r] * resc[r] + psum[r];
      }
#pragma unroll
      for (int d = 0; d < 8; d++)
#pragma unroll
        for (int r = 0; r < 4; r++) accO[d][r] *= resc[r];

      asm volatile("s_waitcnt lgkmcnt(0)" ::: "memory");
      short8 pf[2];
#pragma unroll
      for (int k2 = 0; k2 < 2; k2++)
        pf[k2] = *(const short8*)&P_lds[wave][llo][k2 * 32 + lhi * 8];
#pragma unroll
      for (int d = 0; d < 8; d++)
#pragma unroll
        for (int k2 = 0; k2 < 2; k2++) {
          short8 vfr = *(const short8*)&Vts[(size_t)(h * HDIM + d * 16 + llo) * N_TOK +
                                            offh + c0 + k2 * 32 + lhi * 8];
          accO[d] = __builtin_amdgcn_mfma_f32_16x16x32_bf16(pf[k2], vfr, accO[d], 0, 0, 0);
        }
      asm volatile("" ::: "memory");
    }

#pragma unroll
    for (int r = 0; r < 4; r++) {
      int rl = qbase + lhi * 4 + r;
      if (rl < bs) {
        int tok = perm[off + rl];
        float inv = 1.f / l[r];
#pragma unroll
        for (int d = 0; d < 8; d++)
          ob[(size_t)tok * D_MODEL + h * HDIM + d * 16 + llo] = f2bf(accO[d][r] * inv);
      }
    }
  }
}

extern "C" void kernel_launch(void* const* d_in, const int* in_sizes, int n_in,
                              void* d_out, int out_size, void* d_ws, size_t ws_size,
                              hipStream_t stream) {
  const float* x  = (const float*)d_in[0];
  const float* Wq = (const float*)d_in[1];
  const float* bq = (const float*)d_in[2];
  const float* Wk = (const float*)d_in[3];
  const float* bk = (const float*)d_in[4];
  const float* Wv = (const float*)d_in[5];
  const float* bv = (const float*)d_in[6];
  const float* Wo = (const float*)d_in[7];
  const float* bo = (const float*)d_in[8];
  const float* hp = (const float*)d_in[9];
  float* out = (float*)d_out;

  char* ws = (char*)d_ws;
  size_t off = 0;
  auto alloc = [&](size_t b) {
    char* p = ws + off;
    off += (b + 255) & ~(size_t)255;
    return p;
  };

  const int N = N_TOK, D = D_MODEL;
  u16* xhi    = (u16*)alloc((size_t)N * D * 2);
  u16* xlo    = (u16*)alloc((size_t)N * D * 2);
  u16* wqt_hi = (u16*)alloc((size_t)D * D * 2);
  u16* wqt_lo = (u16*)alloc((size_t)D * D * 2);
  u16* kvt    = (u16*)alloc((size_t)2 * D * D * 2);
  u16* wot    = (u16*)alloc((size_t)D * D * 2);
  float* Qf   = (float*)alloc((size_t)N * D * 4);
  u16* qbb    = (u16*)alloc((size_t)N * D * 2);
  u16* kbb    = (u16*)alloc((size_t)N * D * 2);
  u16* vbb    = (u16*)alloc((size_t)N * D * 2);
  u16* Vts    = (u16*)alloc((size_t)N_HEAD * HDIM * N * 2 + 256);
  int* bucket = (int*)alloc((size_t)N_HEAD * N * 4);
  int* counts = (int*)alloc(512 * 4);
  int* offs   = (int*)alloc(512 * 4);
  int* perm   = (int*)alloc((size_t)N_HEAD * N * 4);
  int* wl     = (int*)alloc(WL_CAP * 4);
  int* wlcnt  = (int*)alloc(256);
  u16* ob     = (u16*)alloc((size_t)N * D * 2);

  const int nelem = N * D;

  split_cast_kernel<<<(nelem + 255) / 256, 256, 0, stream>>>(x, xhi, xlo, nelem);
  transpose_all_kernel<<<dim3(32, 32, 4), 256, 0, stream>>>(
      Wq, Wk, Wv, Wo, wqt_hi, wqt_lo, kvt, wot);

  gemm3_bf16_kernel<<<(N / 64) * (D / 128), 256, 0, stream>>>(
      xhi, xlo, wqt_hi, wqt_lo, Qf, bq, qbb, D, D);
  gemm_bf16_kernel<64><<<(N / 64) * (2 * D / 128), 256, 0, stream>>>(
      xhi, kvt, nullptr, bk, bv, kbb, vbb, 2 * D, D, 2 | 8);

  hash_argmax_kernel<<<dim3(N / 64, N_HEAD), 256, 0, stream>>>(Qf, hp, bucket);
  bucket_count_kernel<<<512, 64, 0, stream>>>(bucket, counts);
  build_wl_kernel<<<1, 512, 0, stream>>>(counts, offs, wl, wlcnt);
  bucket_fill_kernel<<<512, 64, 0, stream>>>(bucket, offs, perm);
  gather_vt_kernel<<<512, 256, 0, stream>>>(vbb, perm, Vts);

  attn_bucket_kernel<<<ATTN_BLOCKS, 256, 0, stream>>>(
      qbb, kbb, Vts, perm, offs, counts, wl, wlcnt, ob);

  gemm_bf16_kernel<64><<<(N / 64) * (D / 128), 256, 0, stream>>>(
      ob, wot, out, bo, nullptr, nullptr, nullptr, D, D, 2);

  (void)in_sizes; (void)n_in; (void)out_size; (void)ws_size;
}